// Round 4
// baseline (466.592 us; speedup 1.0000x reference)
//
#include <hip/hip_runtime.h>

#define NROWS 500000
#define DD 128
#define NSTACK 12
#define BNEPS 1e-3f
#define NCOL 50
#define TRS 51            // trow stride in floats (204B: odd -> conflict-free reads)
#define PERSIST 768       // 256 CU x 3 blocks/CU
#define NT_WAVE ((NROWS + 63) / 64)   // 7813 wave-tiles (64 rows each)
#define CTR_INIT (PERSIST * 4)        // 3072 static initial wave-tiles

typedef float  v2f    __attribute__((ext_vector_type(2)));
typedef float  v4f    __attribute__((ext_vector_type(4)));
typedef float  f32x4  __attribute__((ext_vector_type(4)));
typedef __bf16 bf16x8 __attribute__((ext_vector_type(8)));

__device__ __forceinline__ unsigned short f2bf_rn(float f) {
    unsigned u = __float_as_uint(f);
    return (unsigned short)((u + 0x7FFFu + ((u >> 16) & 1u)) >> 16);
}

// -------- workspace layout (bytes) --------
//  [0,     16384)  ushort frag[4][4][64][8]   B fragments, bf16, MFMA fragment order
//  [16384, 16576)  float  SC[48]              gamma * rsqrt(var+eps)
//  [16576, 16768)  float  SH[48]              beta  - mean * SC
//  [16768, 16776)  float  BF2[2]              final bias
//  [16784, 16788)  int    CTR                 work-stealing counter

__global__ void prep_kernel(
    const float* __restrict__ w0,  const float* __restrict__ w1,
    const float* __restrict__ w2,  const float* __restrict__ w3,
    const float* __restrict__ w4,  const float* __restrict__ w5,
    const float* __restrict__ w6,  const float* __restrict__ w7,
    const float* __restrict__ w8,  const float* __restrict__ w9,
    const float* __restrict__ w10, const float* __restrict__ w11,
    const float* __restrict__ gamma_, const float* __restrict__ beta_,
    const float* __restrict__ mean_,  const float* __restrict__ var_,
    const float* __restrict__ wf,     const float* __restrict__ bfv,
    unsigned short* __restrict__ frag, float* __restrict__ sc,
    float* __restrict__ sh, float* __restrict__ bf2, int* __restrict__ ctr)
{
    const float* ws[NSTACK] = {w0,w1,w2,w3,w4,w5,w6,w7,w8,w9,w10,w11};
    const int f    = blockIdx.x * 256 + threadIdx.x;   // 0..8191
    const int j    = f & 7;
    const int lane = (f >> 3) & 63;
    const int nt   = (f >> 9) & 3;
    const int kt   = f >> 11;
    const int k    = kt * 32 + (lane >> 4) * 8 + j;
    const int n    = nt * 16 + (lane & 15);

    float val = 0.f;
    if (n < 48) {
        const int i = n >> 2, u = n & 3;
        val = ws[i][16 * i + 4 * k + u];
    } else if (n < NCOL) {
        val = wf[96 + 2 * k + (n - 48)];
    }
    frag[f] = f2bf_rn(val);

    if (blockIdx.x == 0) {
        if (threadIdx.x < 48) {
            const float s = gamma_[threadIdx.x] * __frsqrt_rn(var_[threadIdx.x] + BNEPS);
            sc[threadIdx.x] = s;
            sh[threadIdx.x] = beta_[threadIdx.x] - mean_[threadIdx.x] * s;
        }
        if (threadIdx.x < 2) bf2[threadIdx.x] = bfv[threadIdx.x];
        if (threadIdx.x == 0) *ctr = CTR_INIT;        // reset each launch (ws re-poisoned)
    }
}

// Persistent main kernel, wave-level work stealing. Each WAVE independently
// processes 64-row tiles: static tile = global wave id, then atomicAdd steal.
// Per tile: phase1 MFMA (kt=0 from prefetch regs) -> transpose -> steal next
// tile + issue its kt=0 prefetch -> phase2/3 VALU (hides steal + HBM latency).
// No __syncthreads anywhere; waves fully decoupled (trow regions wave-private).
__global__ __launch_bounds__(256, 3) void predict_kernel(
    const float* __restrict__ x,
    const float* __restrict__ w0,  const float* __restrict__ w1,
    const float* __restrict__ w2,  const float* __restrict__ w3,
    const float* __restrict__ w4,  const float* __restrict__ w5,
    const float* __restrict__ w6,  const float* __restrict__ w7,
    const float* __restrict__ w8,  const float* __restrict__ w9,
    const float* __restrict__ w10, const float* __restrict__ w11,
    const float* __restrict__ wf,
    const unsigned short* __restrict__ frag,
    const float* __restrict__ SCg, const float* __restrict__ SHg,
    const float* __restrict__ BFg, int* __restrict__ ctr,
    float* __restrict__ out)
{
    __shared__ __align__(16) float trow[256 * TRS];   // 52224 B -> 3 blocks/CU

    const int tid  = threadIdx.x;
    const int lane = tid & 63;
    const int wv   = tid >> 6;
    const int m = lane & 15;
    const int q = lane >> 4;
    float* tr = &trow[wv * 64 * TRS];
    const float* myT = &trow[(wv * 64 + lane) * TRS];
    const float* ws[NSTACK] = {w0,w1,w2,w3,w4,w5,w6,w7,w8,w9,w10,w11};

    int T = blockIdx.x * 4 + wv;                      // static first tile

    // current-tile row pointers (clamped; tail stores predicated)
    const float* arow[4];
#pragma unroll
    for (int mt = 0; mt < 4; ++mt) {
        int r = T * 64 + mt * 16 + m;
        if (r > NROWS - 1) r = NROWS - 1;
        arow[mt] = x + (size_t)r * DD + q * 8;
    }

    // prologue: prefetch kt=0 A-data for the first tile
    v4f pf0[4], pf1[4];
#pragma unroll
    for (int mt = 0; mt < 4; ++mt) {
        pf0[mt] = *(const v4f*)(arow[mt]);
        pf1[mt] = *(const v4f*)(arow[mt] + 4);
    }

    for (;;) {
        // ---- Phase 1: MFMA GEMM ----
        f32x4 acc[4][4];
#pragma unroll
        for (int mt = 0; mt < 4; ++mt)
#pragma unroll
            for (int nt = 0; nt < 4; ++nt) acc[mt][nt] = (f32x4){0.f, 0.f, 0.f, 0.f};

        // kt = 0: A from prefetch registers
        {
            bf16x8 bfrag[4];
#pragma unroll
            for (int nt = 0; nt < 4; ++nt)
                bfrag[nt] = *(const bf16x8*)(frag + ((nt * 64 + lane) << 3));
#pragma unroll
            for (int mt = 0; mt < 4; ++mt) {
                bf16x8 av;
#pragma unroll
                for (int e = 0; e < 4; ++e) {
                    av[e]     = (__bf16)pf0[mt][e];   // v_cvt_pk_bf16_f32
                    av[4 + e] = (__bf16)pf1[mt][e];
                }
#pragma unroll
                for (int nt = 0; nt < 4; ++nt)
                    acc[mt][nt] = __builtin_amdgcn_mfma_f32_16x16x32_bf16(
                        av, bfrag[nt], acc[mt][nt], 0, 0, 0);
            }
        }

        // kt = 1..3: A streamed per-mt (low register pressure)
#pragma unroll
        for (int kt = 1; kt < 4; ++kt) {
            bf16x8 bfrag[4];
#pragma unroll
            for (int nt = 0; nt < 4; ++nt)
                bfrag[nt] = *(const bf16x8*)(frag + (((kt * 4 + nt) * 64 + lane) << 3));
#pragma unroll
            for (int mt = 0; mt < 4; ++mt) {
                const v4f a0 = *(const v4f*)(arow[mt] + kt * 32);
                const v4f a1 = *(const v4f*)(arow[mt] + kt * 32 + 4);
                bf16x8 av;
#pragma unroll
                for (int e = 0; e < 4; ++e) {
                    av[e]     = (__bf16)a0[e];
                    av[4 + e] = (__bf16)a1[e];
                }
#pragma unroll
                for (int nt = 0; nt < 4; ++nt)
                    acc[mt][nt] = __builtin_amdgcn_mfma_f32_16x16x32_bf16(
                        av, bfrag[nt], acc[mt][nt], 0, 0, 0);
            }
        }

        // ---- Phase 1.5: C-frag -> row-major LDS (wave-private region) ----
        // C/D layout: col = lane&15, row = (lane>>4)*4 + reg   [m89/m91]
#pragma unroll
        for (int mt = 0; mt < 4; ++mt)
#pragma unroll
            for (int nt = 0; nt < 4; ++nt) {
                const int c = nt * 16 + m;
                if (c < NCOL) {
#pragma unroll
                    for (int r = 0; r < 4; ++r)
                        tr[(mt * 16 + q * 4 + r) * TRS + c] = acc[mt][nt][r];
                }
            }

        // ---- steal next tile; issue its kt=0 prefetch (hides under ph2/3) ----
        int Tn;
        if (lane == 0) Tn = atomicAdd(ctr, 1);
        Tn = __shfl(Tn, 0);                           // wave-uniform
        const bool more = (Tn < NT_WAVE);
        if (more) {
#pragma unroll
            for (int mt = 0; mt < 4; ++mt) {
                int r = Tn * 64 + mt * 16 + m;
                if (r > NROWS - 1) r = NROWS - 1;
                arow[mt] = x + (size_t)r * DD + q * 8;   // becomes current next iter
            }
#pragma unroll
            for (int mt = 0; mt < 4; ++mt) {
                pf0[mt] = *(const v4f*)(arow[mt]);
                pf1[mt] = *(const v4f*)(arow[mt] + 4);
            }
        }

        // ---- Phase 2: per-lane recurrence, packed fp32 (v_pk_fma_f32) ----
        v2f y2[NSTACK * 2];                           // even-aligned pairs
#pragma unroll
        for (int i = 0; i < NSTACK; ++i) {
            v2f a01 = *(const v2f*)(myT + 4 * i);
            v2f a23 = *(const v2f*)(myT + 4 * i + 2);
            const float* wsi = ws[i];
#pragma unroll
            for (int mr = 0; mr < 4 * i; ++mr) {      // uniform idx -> s_load (K$)
                const int yi = (i - 1 - (mr >> 2)) * 4 + (mr & 3);
                const float hvs = y2[yi >> 1][yi & 1];
                const v2f hv2 = {hvs, hvs};           // op_sel splat
                a01 += hv2 * (*(const v2f*)(wsi + 4 * mr));
                a23 += hv2 * (*(const v2f*)(wsi + 4 * mr + 2));
            }
            const v2f sc01 = *(const v2f*)(SCg + 4 * i);
            const v2f sc23 = *(const v2f*)(SCg + 4 * i + 2);
            const v2f sh01 = *(const v2f*)(SHg + 4 * i);
            const v2f sh23 = *(const v2f*)(SHg + 4 * i + 2);
            v2f r01 = a01 * sc01 + sh01;
            v2f r23 = a23 * sc23 + sh23;
            r01.x = fmaxf(r01.x, 0.f); r01.y = fmaxf(r01.y, 0.f);
            r23.x = fmaxf(r23.x, 0.f); r23.y = fmaxf(r23.y, 0.f);
            y2[2 * i]     = r01;
            y2[2 * i + 1] = r23;
        }

        // ---- Phase 3: final logits (packed) + softmax ----
        v2f l01 = *(const v2f*)(myT + 48) + *(const v2f*)BFg;
#pragma unroll
        for (int mr = 0; mr < 48; ++mr) {             // uniform idx -> s_load (K$)
            const int yi = (11 - (mr >> 2)) * 4 + (mr & 3);
            const float hvs = y2[yi >> 1][yi & 1];
            const v2f hv2 = {hvs, hvs};
            l01 += hv2 * (*(const v2f*)(wf + 2 * mr));
        }

        const float mx = fmaxf(l01.x, l01.y);
        const float e0 = __expf(l01.x - mx);
        const float e1 = __expf(l01.y - mx);
        const float inv = 1.0f / (e0 + e1);

        const int row = T * 64 + lane;
        if (row < NROWS)
            *(v2f*)(out + (size_t)row * 2) = (v2f){e0 * inv, e1 * inv};

        if (!more) break;
        T = Tn;
    }
}

extern "C" void kernel_launch(void* const* d_in, const int* in_sizes, int n_in,
                              void* d_out, int out_size, void* d_ws, size_t ws_size,
                              hipStream_t stream) {
    const float* x   = (const float*)d_in[0];
    const float* w0  = (const float*)d_in[1];
    const float* w1  = (const float*)d_in[2];
    const float* w2  = (const float*)d_in[3];
    const float* w3  = (const float*)d_in[4];
    const float* w4  = (const float*)d_in[5];
    const float* w5  = (const float*)d_in[6];
    const float* w6  = (const float*)d_in[7];
    const float* w7  = (const float*)d_in[8];
    const float* w8  = (const float*)d_in[9];
    const float* w9  = (const float*)d_in[10];
    const float* w10 = (const float*)d_in[11];
    const float* w11 = (const float*)d_in[12];
    const float* gm  = (const float*)d_in[13];
    const float* bt  = (const float*)d_in[14];
    const float* mn  = (const float*)d_in[15];
    const float* vr  = (const float*)d_in[16];
    const float* wf  = (const float*)d_in[17];
    const float* bf  = (const float*)d_in[18];
    float* out = (float*)d_out;

    unsigned short* frag = (unsigned short*)d_ws;
    float* SCg = (float*)((char*)d_ws + 16384);
    float* SHg = (float*)((char*)d_ws + 16576);
    float* BFg = (float*)((char*)d_ws + 16768);
    int*   CTR = (int*)((char*)d_ws + 16784);

    hipLaunchKernelGGL(prep_kernel, dim3(32), dim3(256), 0, stream,
                       w0, w1, w2, w3, w4, w5, w6, w7, w8, w9, w10, w11,
                       gm, bt, mn, vr, wf, bf, frag, SCg, SHg, BFg, CTR);

    hipLaunchKernelGGL(predict_kernel, dim3(PERSIST), dim3(256), 0, stream,
                       x, w0, w1, w2, w3, w4, w5, w6, w7, w8, w9, w10, w11,
                       wf, frag, SCg, SHg, BFg, CTR, out);
}

// Round 5
// 390.745 us; speedup vs baseline: 1.1941x; 1.1941x over previous
//
#include <hip/hip_runtime.h>

#define NROWS 500000
#define DD 128
#define NSTACK 12
#define BNEPS 1e-3f
#define NCOL 50
#define TRS 51            // trow stride in floats (204B: odd stride -> <=2-way LDS banking)

typedef float  v2f    __attribute__((ext_vector_type(2)));
typedef float  v4f    __attribute__((ext_vector_type(4)));
typedef float  f32x4  __attribute__((ext_vector_type(4)));
typedef __bf16 bf16x8 __attribute__((ext_vector_type(8)));

__device__ __forceinline__ unsigned short f2bf_rn(float f) {
    unsigned u = __float_as_uint(f);
    return (unsigned short)((u + 0x7FFFu + ((u >> 16) & 1u)) >> 16);
}

// -------- workspace layout (bytes) --------
//  [0,     16384)  ushort frag[4][4][64][8]   B fragments, bf16, MFMA fragment order
//  [16384, 16576)  float  SC[48]              gamma * rsqrt(var+eps)
//  [16576, 16768)  float  SH[48]              beta  - mean * SC
//  [16768, 16776)  float  BF2[2]              final bias

__global__ void prep_kernel(
    const float* __restrict__ w0,  const float* __restrict__ w1,
    const float* __restrict__ w2,  const float* __restrict__ w3,
    const float* __restrict__ w4,  const float* __restrict__ w5,
    const float* __restrict__ w6,  const float* __restrict__ w7,
    const float* __restrict__ w8,  const float* __restrict__ w9,
    const float* __restrict__ w10, const float* __restrict__ w11,
    const float* __restrict__ gamma_, const float* __restrict__ beta_,
    const float* __restrict__ mean_,  const float* __restrict__ var_,
    const float* __restrict__ wf,     const float* __restrict__ bfv,
    unsigned short* __restrict__ frag, float* __restrict__ sc,
    float* __restrict__ sh, float* __restrict__ bf2)
{
    const float* ws[NSTACK] = {w0,w1,w2,w3,w4,w5,w6,w7,w8,w9,w10,w11};
    const int f    = blockIdx.x * 256 + threadIdx.x;   // 0..8191
    const int j    = f & 7;
    const int lane = (f >> 3) & 63;
    const int nt   = (f >> 9) & 3;
    const int kt   = f >> 11;
    const int k    = kt * 32 + (lane >> 4) * 8 + j;
    const int n    = nt * 16 + (lane & 15);

    float val = 0.f;
    if (n < 48) {
        const int i = n >> 2, u = n & 3;
        val = ws[i][16 * i + 4 * k + u];
    } else if (n < NCOL) {
        val = wf[96 + 2 * k + (n - 48)];
    }
    frag[f] = f2bf_rn(val);

    if (blockIdx.x == 0) {
        if (threadIdx.x < 48) {
            const float s = gamma_[threadIdx.x] * __frsqrt_rn(var_[threadIdx.x] + BNEPS);
            sc[threadIdx.x] = s;
            sh[threadIdx.x] = beta_[threadIdx.x] - mean_[threadIdx.x] * s;
        }
        if (threadIdx.x < 2) bf2[threadIdx.x] = bfv[threadIdx.x];
    }
}

// Main kernel: 4 waves x 64 rows = 256 rows/block, one tile per block,
// no __syncthreads anywhere (trow regions are wave-private).
// Phase 1: MFMA GEMM with a kt-axis register ping-pong: all 8 A-loads of
//          kt+1 are issued before computing kt (straight-line, no branches,
//          so the scheduler keeps ~8 HBM loads in flight at all times).
// Phase 2/3: packed-fp32 recurrence (v_pk_fma_f32), weights via scalar K$.
__global__ __launch_bounds__(256, 3) void predict_kernel(
    const float* __restrict__ x,
    const float* __restrict__ w0,  const float* __restrict__ w1,
    const float* __restrict__ w2,  const float* __restrict__ w3,
    const float* __restrict__ w4,  const float* __restrict__ w5,
    const float* __restrict__ w6,  const float* __restrict__ w7,
    const float* __restrict__ w8,  const float* __restrict__ w9,
    const float* __restrict__ w10, const float* __restrict__ w11,
    const float* __restrict__ wf,
    const unsigned short* __restrict__ frag,
    const float* __restrict__ SCg, const float* __restrict__ SHg,
    const float* __restrict__ BFg,
    float* __restrict__ out)
{
    __shared__ __align__(16) float trow[256 * TRS];   // 52224 B -> 3 blocks/CU

    const int tid  = threadIdx.x;
    const int lane = tid & 63;
    const int wv   = tid >> 6;
    const int rowbase = blockIdx.x * 256 + wv * 64;
    const int m = lane & 15;
    const int q = lane >> 4;

    // ---- Phase 1: MFMA GEMM ----
    const float* arow[4];
#pragma unroll
    for (int mt = 0; mt < 4; ++mt) {
        int r = rowbase + mt * 16 + m;
        if (r > NROWS - 1) r = NROWS - 1;             // tail clamp (stores predicated)
        arow[mt] = x + (size_t)r * DD + q * 8;
    }

    f32x4 acc[4][4];
#pragma unroll
    for (int mt = 0; mt < 4; ++mt)
#pragma unroll
        for (int nt = 0; nt < 4; ++nt) acc[mt][nt] = (f32x4){0.f, 0.f, 0.f, 0.f};

    // prologue: kt=0 A-loads in flight
    v4f pa0[4], pa1[4];
#pragma unroll
    for (int mt = 0; mt < 4; ++mt) {
        pa0[mt] = *(const v4f*)(arow[mt]);
        pa1[mt] = *(const v4f*)(arow[mt] + 4);
    }

#pragma unroll
    for (int kt = 0; kt < 4; ++kt) {
        // B fragments for this kt (L2-resident, short latency)
        bf16x8 bfrag[4];
#pragma unroll
        for (int nt = 0; nt < 4; ++nt)
            bfrag[nt] = *(const bf16x8*)(frag + (((kt * 4 + nt) * 64 + lane) << 3));

        // issue next kt's A-loads before touching this kt's data
        v4f na0[4], na1[4];
        if (kt < 3) {
#pragma unroll
            for (int mt = 0; mt < 4; ++mt) {
                na0[mt] = *(const v4f*)(arow[mt] + (kt + 1) * 32);
                na1[mt] = *(const v4f*)(arow[mt] + (kt + 1) * 32 + 4);
            }
        }

        // compute on the in-flight kt data
#pragma unroll
        for (int mt = 0; mt < 4; ++mt) {
            bf16x8 av;
#pragma unroll
            for (int e = 0; e < 4; ++e) {
                av[e]     = (__bf16)pa0[mt][e];       // v_cvt_pk_bf16_f32
                av[4 + e] = (__bf16)pa1[mt][e];
            }
#pragma unroll
            for (int nt = 0; nt < 4; ++nt)
                acc[mt][nt] = __builtin_amdgcn_mfma_f32_16x16x32_bf16(
                    av, bfrag[nt], acc[mt][nt], 0, 0, 0);
        }

        if (kt < 3) {
#pragma unroll
            for (int mt = 0; mt < 4; ++mt) {          // SSA renames, no real movs
                pa0[mt] = na0[mt];
                pa1[mt] = na1[mt];
            }
        }
    }

    // ---- Phase 1.5: C-frag -> row-major LDS (wave-private region) ----
    // C/D layout: col = lane&15, row = (lane>>4)*4 + reg   [m89/m91]
    float* tr = &trow[wv * 64 * TRS];
#pragma unroll
    for (int mt = 0; mt < 4; ++mt)
#pragma unroll
        for (int nt = 0; nt < 4; ++nt) {
            const int c = nt * 16 + m;
            if (c < NCOL) {
#pragma unroll
                for (int r = 0; r < 4; ++r)
                    tr[(mt * 16 + q * 4 + r) * TRS + c] = acc[mt][nt][r];
            }
        }

    // ---- Phase 2: per-lane recurrence, packed fp32 (v_pk_fma_f32) ----
    const float* myT = &trow[(wv * 64 + lane) * TRS];
    const float* ws[NSTACK] = {w0,w1,w2,w3,w4,w5,w6,w7,w8,w9,w10,w11};

    v2f y2[NSTACK * 2];                               // even-aligned pairs
#pragma unroll
    for (int i = 0; i < NSTACK; ++i) {
        v2f a01 = *(const v2f*)(myT + 4 * i);         // ds_read_b64, <=2-way banks
        v2f a23 = *(const v2f*)(myT + 4 * i + 2);
        const float* wsi = ws[i];
#pragma unroll
        for (int mr = 0; mr < 4 * i; ++mr) {          // uniform idx -> s_load (K$)
            const int yi = (i - 1 - (mr >> 2)) * 4 + (mr & 3);
            const float hvs = y2[yi >> 1][yi & 1];
            const v2f hv2 = {hvs, hvs};               // op_sel splat
            a01 += hv2 * (*(const v2f*)(wsi + 4 * mr));
            a23 += hv2 * (*(const v2f*)(wsi + 4 * mr + 2));
        }
        const v2f sc01 = *(const v2f*)(SCg + 4 * i);
        const v2f sc23 = *(const v2f*)(SCg + 4 * i + 2);
        const v2f sh01 = *(const v2f*)(SHg + 4 * i);
        const v2f sh23 = *(const v2f*)(SHg + 4 * i + 2);
        v2f r01 = a01 * sc01 + sh01;
        v2f r23 = a23 * sc23 + sh23;
        r01.x = fmaxf(r01.x, 0.f); r01.y = fmaxf(r01.y, 0.f);
        r23.x = fmaxf(r23.x, 0.f); r23.y = fmaxf(r23.y, 0.f);
        y2[2 * i]     = r01;
        y2[2 * i + 1] = r23;
    }

    // ---- Phase 3: final logits (packed) + softmax ----
    v2f l01 = *(const v2f*)(myT + 48) + *(const v2f*)BFg;
#pragma unroll
    for (int mr = 0; mr < 48; ++mr) {                 // uniform idx -> s_load (K$)
        const int yi = (11 - (mr >> 2)) * 4 + (mr & 3);
        const float hvs = y2[yi >> 1][yi & 1];
        const v2f hv2 = {hvs, hvs};
        l01 += hv2 * (*(const v2f*)(wf + 2 * mr));
    }

    const float mx = fmaxf(l01.x, l01.y);
    const float e0 = __expf(l01.x - mx);
    const float e1 = __expf(l01.y - mx);
    const float inv = 1.0f / (e0 + e1);

    const int row = rowbase + lane;
    if (row < NROWS)
        *(v2f*)(out + (size_t)row * 2) = (v2f){e0 * inv, e1 * inv};
}

extern "C" void kernel_launch(void* const* d_in, const int* in_sizes, int n_in,
                              void* d_out, int out_size, void* d_ws, size_t ws_size,
                              hipStream_t stream) {
    const float* x   = (const float*)d_in[0];
    const float* w0  = (const float*)d_in[1];
    const float* w1  = (const float*)d_in[2];
    const float* w2  = (const float*)d_in[3];
    const float* w3  = (const float*)d_in[4];
    const float* w4  = (const float*)d_in[5];
    const float* w5  = (const float*)d_in[6];
    const float* w6  = (const float*)d_in[7];
    const float* w7  = (const float*)d_in[8];
    const float* w8  = (const float*)d_in[9];
    const float* w9  = (const float*)d_in[10];
    const float* w10 = (const float*)d_in[11];
    const float* w11 = (const float*)d_in[12];
    const float* gm  = (const float*)d_in[13];
    const float* bt  = (const float*)d_in[14];
    const float* mn  = (const float*)d_in[15];
    const float* vr  = (const float*)d_in[16];
    const float* wf  = (const float*)d_in[17];
    const float* bf  = (const float*)d_in[18];
    float* out = (float*)d_out;

    unsigned short* frag = (unsigned short*)d_ws;
    float* SCg = (float*)((char*)d_ws + 16384);
    float* SHg = (float*)((char*)d_ws + 16576);
    float* BFg = (float*)((char*)d_ws + 16768);

    hipLaunchKernelGGL(prep_kernel, dim3(32), dim3(256), 0, stream,
                       w0, w1, w2, w3, w4, w5, w6, w7, w8, w9, w10, w11,
                       gm, bt, mn, vr, wf, bf, frag, SCg, SHg, BFg);

    dim3 block(256);
    dim3 grid((NROWS + 255) / 256);   // 256 rows per block
    hipLaunchKernelGGL(predict_kernel, grid, block, 0, stream,
                       x, w0, w1, w2, w3, w4, w5, w6, w7, w8, w9, w10, w11,
                       wf, frag, SCg, SHg, BFg, out);
}